// Round 2
// baseline (66.355 us; speedup 1.0000x reference)
//
#include <hip/hip_runtime.h>
#include <hip/hip_bf16.h>
#include <stdint.h>

typedef __attribute__((ext_vector_type(8))) __bf16 bf16x8;
typedef __attribute__((ext_vector_type(4))) float f32x4;

static constexpr int Bb = 32, Ss = 512, Dd = 1024, Rr = 256, Nn = 512;
static constexpr int M1 = Bb * Ss;  // 16384

__device__ __forceinline__ void gload_lds16(const void* g, void* l) {
  __builtin_amdgcn_global_load_lds(
      (const __attribute__((address_space(1))) void*)g,
      (__attribute__((address_space(3))) void*)l, 16, 0, 0);
}

// ---- prep: Bt[512][1024] bf16. rows 0-255 = L^T, rows 256-511 = R ----------
__global__ __launch_bounds__(256) void prep_kernel(
    const float* __restrict__ L, const float* __restrict__ R,
    __bf16* __restrict__ Bt) {
  int i = blockIdx.x * 256 + threadIdx.x;  // 0 .. 512*1024-1 exactly
  int n = i >> 10;
  int d = i & (Dd - 1);
  float v = (n < Rr) ? L[d * Rr + n] : R[(size_t)(n - Rr) * Dd + d];
  Bt[i] = (__bf16)v;
}

// ---- stage 1: C[16384,512] = batch_f32[16384,1024] x Bt[512,1024]^T --------
// 128x128 tile, BK=64, double-buffered LDS (64KB), 4 waves.
// A: reg-staged (issue-early / cvt+write-late, T14), swizzled ds_write.
// B: global_load_lds w/ pre-swizzled source (rule 21). Swizzle: g ^= row&7.
__global__ __launch_bounds__(256, 2) void proj_gemm(
    const float* __restrict__ batch,
    const __bf16* __restrict__ Bt,   // [512][1024]
    __bf16* __restrict__ outL,       // [16384][256]
    __bf16* __restrict__ outR) {     // [16384][256]
  const int nt = blockIdx.x;  // 0..3
  const int mt = blockIdx.y;  // 0..127
  const int m0 = mt * 128, n0 = nt * 128;

  __shared__ __align__(16) char smem[65536];
  // A bufs at 0,16384; B bufs at 32768,49152. Each tile 128 rows x 128B.

  const int t = threadIdx.x;
  const int lane = t & 63;
  const int wave = t >> 6;
  const int wr = wave >> 1, wc = wave & 1;

  f32x4 acc[4][4] = {};
  f32x4 areg[8];

  // per-thread staging coords: 4 granules, e = q*256+t, row=e>>3, g=e&7
  auto issueA = [&](int k0) {
#pragma unroll
    for (int q = 0; q < 4; ++q) {
      int e = q * 256 + t;
      int row = e >> 3, g = e & 7;
      const float* src = batch + (size_t)(m0 + row) * Dd + k0 + g * 8;
      areg[2 * q] = *(const f32x4*)src;
      areg[2 * q + 1] = *(const f32x4*)(src + 4);
    }
  };
  auto writeA = [&](int buf) {
    char* Ab = smem + buf * 16384;
#pragma unroll
    for (int q = 0; q < 4; ++q) {
      int e = q * 256 + t;
      int row = e >> 3, g = e & 7;
      int gs = g ^ (row & 7);
      bf16x8 v;
      f32x4 f0 = areg[2 * q], f1 = areg[2 * q + 1];
      v[0] = (__bf16)f0[0]; v[1] = (__bf16)f0[1];
      v[2] = (__bf16)f0[2]; v[3] = (__bf16)f0[3];
      v[4] = (__bf16)f1[0]; v[5] = (__bf16)f1[1];
      v[6] = (__bf16)f1[2]; v[7] = (__bf16)f1[3];
      *(bf16x8*)(Ab + (row * 8 + gs) * 16) = v;
    }
  };
  auto stageB = [&](int buf, int k0) {
    char* Bbuf = smem + 32768 + buf * 16384;
#pragma unroll
    for (int p = 0; p < 4; ++p) {
      int e = p * 256 + t;
      int row = e >> 3, g = e & 7;
      int gs = g ^ (row & 7);  // pre-swizzled SOURCE, linear LDS dest
      gload_lds16(Bt + (size_t)(n0 + row) * Dd + k0 + gs * 8,
                  Bbuf + e * 16);
    }
  };
  auto compute = [&](int buf) {
    char* Ab = smem + buf * 16384;
    char* Bbuf = smem + 32768 + buf * 16384;
#pragma unroll
    for (int kk = 0; kk < 2; ++kk) {
      bf16x8 a[4], b[4];
#pragma unroll
      for (int m = 0; m < 4; ++m) {
        int row = wr * 64 + m * 16 + (lane & 15);
        int g = kk * 4 + (lane >> 4);
        a[m] = *(const bf16x8*)(Ab + (row * 8 + (g ^ (row & 7))) * 16);
      }
#pragma unroll
      for (int n = 0; n < 4; ++n) {
        int row = wc * 64 + n * 16 + (lane & 15);
        int g = kk * 4 + (lane >> 4);
        b[n] = *(const bf16x8*)(Bbuf + (row * 8 + (g ^ (row & 7))) * 16);
      }
#pragma unroll
      for (int m = 0; m < 4; ++m)
#pragma unroll
        for (int n = 0; n < 4; ++n)
          acc[m][n] = __builtin_amdgcn_mfma_f32_16x16x32_bf16(a[m], b[n],
                                                              acc[m][n], 0, 0, 0);
    }
  };

  // prologue: stage tile 0
  issueA(0);
  stageB(0, 0);
  writeA(0);
  __syncthreads();

  int cur = 0;
  for (int it = 0; it < 16; ++it) {
    int nxt = cur ^ 1;
    if (it < 15) {
      issueA((it + 1) * 64);   // in-flight across the compute phase
      stageB(nxt, (it + 1) * 64);
    }
    compute(cur);
    if (it < 15) writeA(nxt);  // vmcnt auto-inserted before cvt use
    __syncthreads();
    cur = nxt;
  }

  // epilogue: whole block's n-range lies in one half (nt<2 -> L, else R)
  __bf16* out = (n0 < Rr) ? outL : outR;
  const int cb = n0 & (Rr - 1);
  const int col = lane & 15, rgrp = lane >> 4;
#pragma unroll
  for (int m = 0; m < 4; ++m) {
    int r0 = m0 + wr * 64 + m * 16 + rgrp * 4;
#pragma unroll
    for (int n = 0; n < 4; ++n) {
      int c = cb + wc * 64 + n * 16 + col;
#pragma unroll
      for (int i = 0; i < 4; ++i)
        out[(size_t)(r0 + i) * Rr + c] = (__bf16)acc[m][n][i];
    }
  }
}

// ---- stage 2: logits[b] = left[b] @ right[b]^T + bias ----------------------
// Per batch: C[512,512] f32 = A[512,256] x Bt[512,256], both bf16 K-contig.
// Same dbuf+swizzle template, both operands via global_load_lds. 4 K-iters.
__global__ __launch_bounds__(256, 2) void score_gemm(
    const __bf16* __restrict__ left,
    const __bf16* __restrict__ right,
    const float* __restrict__ biasp,
    float* __restrict__ out) {
  const int nt = blockIdx.x;  // 0..3
  const int mt = blockIdx.y;  // 0..3
  const int bz = blockIdx.z;  // 0..31
  const __bf16* A = left + (size_t)bz * Ss * Rr;
  const __bf16* B = right + (size_t)bz * Ss * Rr;
  float* O = out + (size_t)bz * Ss * Ss;
  const int m0 = mt * 128, n0 = nt * 128;

  __shared__ __align__(16) char smem[65536];

  const int t = threadIdx.x;
  const int lane = t & 63;
  const int wave = t >> 6;
  const int wr = wave >> 1, wc = wave & 1;

  f32x4 acc[4][4] = {};

  auto stage = [&](int buf, int k0) {
    char* Ab = smem + buf * 16384;
    char* Bbuf = smem + 32768 + buf * 16384;
#pragma unroll
    for (int p = 0; p < 4; ++p) {
      int e = p * 256 + t;
      int row = e >> 3, g = e & 7;
      int gs = g ^ (row & 7);
      gload_lds16(A + (size_t)(m0 + row) * Rr + k0 + gs * 8, Ab + e * 16);
      gload_lds16(B + (size_t)(n0 + row) * Rr + k0 + gs * 8, Bbuf + e * 16);
    }
  };
  auto compute = [&](int buf) {
    char* Ab = smem + buf * 16384;
    char* Bbuf = smem + 32768 + buf * 16384;
#pragma unroll
    for (int kk = 0; kk < 2; ++kk) {
      bf16x8 a[4], b[4];
#pragma unroll
      for (int m = 0; m < 4; ++m) {
        int row = wr * 64 + m * 16 + (lane & 15);
        int g = kk * 4 + (lane >> 4);
        a[m] = *(const bf16x8*)(Ab + (row * 8 + (g ^ (row & 7))) * 16);
      }
#pragma unroll
      for (int n = 0; n < 4; ++n) {
        int row = wc * 64 + n * 16 + (lane & 15);
        int g = kk * 4 + (lane >> 4);
        b[n] = *(const bf16x8*)(Bbuf + (row * 8 + (g ^ (row & 7))) * 16);
      }
#pragma unroll
      for (int m = 0; m < 4; ++m)
#pragma unroll
        for (int n = 0; n < 4; ++n)
          acc[m][n] = __builtin_amdgcn_mfma_f32_16x16x32_bf16(a[m], b[n],
                                                              acc[m][n], 0, 0, 0);
    }
  };

  stage(0, 0);
  __syncthreads();
  int cur = 0;
  for (int it = 0; it < 4; ++it) {
    int nxt = cur ^ 1;
    if (it < 3) stage(nxt, (it + 1) * 64);
    compute(cur);
    __syncthreads();
    cur = nxt;
  }

  const float bias = *biasp;
  const int col = lane & 15, rgrp = lane >> 4;
#pragma unroll
  for (int m = 0; m < 4; ++m) {
    int r0 = m0 + wr * 64 + m * 16 + rgrp * 4;
#pragma unroll
    for (int n = 0; n < 4; ++n) {
      int c = n0 + wc * 64 + n * 16 + col;
#pragma unroll
      for (int i = 0; i < 4; ++i)
        O[(size_t)(r0 + i) * Ss + c] = acc[m][n][i] + bias;
    }
  }
}

extern "C" void kernel_launch(void* const* d_in, const int* in_sizes, int n_in,
                              void* d_out, int out_size, void* d_ws,
                              size_t ws_size, hipStream_t stream) {
  const float* batch = (const float*)d_in[0];  // [32][512][1024]
  const float* projL = (const float*)d_in[1];  // [1024][256]
  const float* projR = (const float*)d_in[2];  // [256][1024]
  const float* bias = (const float*)d_in[3];   // [1]
  float* out = (float*)d_out;                  // [32][512][512]

  char* ws = (char*)d_ws;
  __bf16* left = (__bf16*)(ws);                 // 8,388,608 B
  __bf16* right = (__bf16*)(ws + 8388608);      // 8,388,608 B
  __bf16* Btc = (__bf16*)(ws + 16777216);       // 1,048,576 B  [512][1024]

  prep_kernel<<<dim3(2048), dim3(256), 0, stream>>>(projL, projR, Btc);
  proj_gemm<<<dim3(4, 128), dim3(256), 0, stream>>>(batch, Btc, left, right);
  score_gemm<<<dim3(4, 4, 32), dim3(256), 0, stream>>>(left, right, bias, out);
}

// Round 3
// 52.022 us; speedup vs baseline: 1.2755x; 1.2755x over previous
//
#include <hip/hip_runtime.h>
#include <hip/hip_bf16.h>
#include <stdint.h>

typedef __attribute__((ext_vector_type(8))) __bf16 bf16x8;
typedef __attribute__((ext_vector_type(4))) float f32x4;

static constexpr int Bb = 32, Ss = 512, Dd = 1024, Rr = 256;

__device__ __forceinline__ void gload_lds16(const void* g, void* l) {
  __builtin_amdgcn_global_load_lds(
      (const __attribute__((address_space(1))) void*)g,
      (__attribute__((address_space(3))) void*)l, 16, 0, 0);
}

// ---- prep: Bt[512][1024] bf16. rows 0-255 = L^T, rows 256-511 = R ----------
__global__ __launch_bounds__(256) void prep_kernel(
    const float* __restrict__ L, const float* __restrict__ R,
    __bf16* __restrict__ Bt) {
  int i = blockIdx.x * 256 + threadIdx.x;  // 0 .. 512*1024-1 exactly
  int n = i >> 10;
  int d = i & (Dd - 1);
  float v = (n < Rr) ? L[d * Rr + n] : R[(size_t)(n - Rr) * Dd + d];
  Bt[i] = (__bf16)v;
}

// ---- stage 1: C[16384,512] = batch_f32[16384,1024] x Bt[512,1024]^T --------
// 64x128 tile, BK=64, single-buffer 32KB LDS, m97 2-barrier loop, 4 blk/CU.
// A staged as fp32 via global_load_lds (cvt on fragment read).
// Swizzle (both sides, rule 21): granule g -> g ^ (row&7), 16B granules.
__global__ __launch_bounds__(256, 4) void proj_gemm(
    const float* __restrict__ batch,
    const __bf16* __restrict__ Bt,   // [512][1024]
    __bf16* __restrict__ outL,       // [16384][256]
    __bf16* __restrict__ outR) {     // [16384][256]
  // XCD-chunked swizzle: 1024 blocks, 8 XCDs -> 128-block chunks.
  const int s = (blockIdx.x & 7) * 128 + (blockIdx.x >> 3);
  const int mt = s >> 2;      // 0..255
  const int nt = s & 3;       // 0..3  (panel-sharing blocks co-XCD)
  const int m0 = mt * 64, n0 = nt * 128;

  __shared__ __align__(16) char smem[32768];
  // A fp32 [64][64]  @ 0      (16KB, 16 granules/row)
  // B bf16 [128][64] @ 16384  (16KB,  8 granules/row)

  const int t = threadIdx.x;
  const int lane = t & 63;
  const int wave = t >> 6;
  const int wr = wave >> 1, wc = wave & 1;  // wave tile 32x64

  f32x4 acc[2][4] = {};

  for (int it = 0; it < 16; ++it) {
    const int k0 = it * 64;
    __syncthreads();  // prior iteration's LDS reads done
#pragma unroll
    for (int q = 0; q < 4; ++q) {  // A: 1024 granules
      int e = q * 256 + t;
      int row = e >> 4, g = e & 15;
      int gsrc = g ^ (row & 7);  // inverse-swizzled SOURCE, linear dest
      gload_lds16(batch + (size_t)(m0 + row) * Dd + k0 + gsrc * 4,
                  smem + e * 16);
    }
#pragma unroll
    for (int q = 0; q < 4; ++q) {  // B: 1024 granules
      int e = q * 256 + t;
      int row = e >> 3, g = e & 7;
      int gsrc = g ^ (row & 7);
      gload_lds16(Bt + (size_t)(n0 + row) * Dd + k0 + gsrc * 8,
                  smem + 16384 + e * 16);
    }
    __syncthreads();  // compiler drains vmcnt before barrier

#pragma unroll
    for (int kk = 0; kk < 2; ++kk) {
      bf16x8 a[2], b[4];
#pragma unroll
      for (int m = 0; m < 2; ++m) {
        int row = wr * 32 + m * 16 + (lane & 15);
        int ga = kk * 8 + (lane >> 4) * 2;  // fp32 granule pair
        f32x4 v0 = *(const f32x4*)(smem + row * 256 + ((ga ^ (row & 7))) * 16);
        f32x4 v1 =
            *(const f32x4*)(smem + row * 256 + (((ga + 1) ^ (row & 7))) * 16);
        bf16x8 av;
        av[0] = (__bf16)v0[0]; av[1] = (__bf16)v0[1];
        av[2] = (__bf16)v0[2]; av[3] = (__bf16)v0[3];
        av[4] = (__bf16)v1[0]; av[5] = (__bf16)v1[1];
        av[6] = (__bf16)v1[2]; av[7] = (__bf16)v1[3];
        a[m] = av;
      }
#pragma unroll
      for (int n = 0; n < 4; ++n) {
        int row = wc * 64 + n * 16 + (lane & 15);
        int g = kk * 4 + (lane >> 4);
        b[n] = *(const bf16x8*)(smem + 16384 +
                                (row * 8 + (g ^ (row & 7))) * 16);
      }
#pragma unroll
      for (int m = 0; m < 2; ++m)
#pragma unroll
        for (int n = 0; n < 4; ++n)
          acc[m][n] = __builtin_amdgcn_mfma_f32_16x16x32_bf16(a[m], b[n],
                                                              acc[m][n], 0, 0, 0);
    }
  }

  // epilogue: n-range lies wholly in L (n0<256) or R half
  __bf16* out = (n0 < Rr) ? outL : outR;
  const int cb = n0 & (Rr - 1);
  const int col = lane & 15, rgrp = lane >> 4;
#pragma unroll
  for (int m = 0; m < 2; ++m) {
    int r0 = m0 + wr * 32 + m * 16 + rgrp * 4;
#pragma unroll
    for (int n = 0; n < 4; ++n) {
      int c = cb + wc * 64 + n * 16 + col;
#pragma unroll
      for (int i = 0; i < 4; ++i)
        out[(size_t)(r0 + i) * Rr + c] = (__bf16)acc[m][n][i];
    }
  }
}

// ---- stage 2: logits[b] = left[b] @ right[b]^T + bias ----------------------
// Per batch: C[512,512] f32 = A[512,256] x Bt[512,256], both bf16 K-contig.
// 64x128 tile, BK=64, single-buffer 24KB, same swizzle. 1024 blocks.
__global__ __launch_bounds__(256, 4) void score_gemm(
    const __bf16* __restrict__ left,
    const __bf16* __restrict__ right,
    const float* __restrict__ biasp,
    float* __restrict__ out) {
  const int nt = blockIdx.x;  // 0..3
  const int mt = blockIdx.y;  // 0..7
  const int bz = blockIdx.z;  // 0..31
  const __bf16* A = left + (size_t)bz * Ss * Rr;
  const __bf16* B = right + (size_t)bz * Ss * Rr;
  float* O = out + (size_t)bz * Ss * Ss;
  const int m0 = mt * 64, n0 = nt * 128;

  __shared__ __align__(16) char smem[24576];
  // A bf16 [64][64] @ 0 (8KB), B bf16 [128][64] @ 8192 (16KB)

  const int t = threadIdx.x;
  const int lane = t & 63;
  const int wave = t >> 6;
  const int wr = wave >> 1, wc = wave & 1;

  f32x4 acc[2][4] = {};

  for (int it = 0; it < 4; ++it) {
    const int k0 = it * 64;
    __syncthreads();
#pragma unroll
    for (int q = 0; q < 2; ++q) {  // A: 512 granules
      int e = q * 256 + t;
      int row = e >> 3, g = e & 7;
      int gsrc = g ^ (row & 7);
      gload_lds16(A + (size_t)(m0 + row) * Rr + k0 + gsrc * 8, smem + e * 16);
    }
#pragma unroll
    for (int q = 0; q < 4; ++q) {  // B: 1024 granules
      int e = q * 256 + t;
      int row = e >> 3, g = e & 7;
      int gsrc = g ^ (row & 7);
      gload_lds16(B + (size_t)(n0 + row) * Rr + k0 + gsrc * 8,
                  smem + 8192 + e * 16);
    }
    __syncthreads();

#pragma unroll
    for (int kk = 0; kk < 2; ++kk) {
      bf16x8 a[2], b[4];
#pragma unroll
      for (int m = 0; m < 2; ++m) {
        int row = wr * 32 + m * 16 + (lane & 15);
        int g = kk * 4 + (lane >> 4);
        a[m] = *(const bf16x8*)(smem + (row * 8 + (g ^ (row & 7))) * 16);
      }
#pragma unroll
      for (int n = 0; n < 4; ++n) {
        int row = wc * 64 + n * 16 + (lane & 15);
        int g = kk * 4 + (lane >> 4);
        b[n] = *(const bf16x8*)(smem + 8192 +
                                (row * 8 + (g ^ (row & 7))) * 16);
      }
#pragma unroll
      for (int m = 0; m < 2; ++m)
#pragma unroll
        for (int n = 0; n < 4; ++n)
          acc[m][n] = __builtin_amdgcn_mfma_f32_16x16x32_bf16(a[m], b[n],
                                                              acc[m][n], 0, 0, 0);
    }
  }

  const float bias = *biasp;
  const int col = lane & 15, rgrp = lane >> 4;
#pragma unroll
  for (int m = 0; m < 2; ++m) {
    int r0 = m0 + wr * 32 + m * 16 + rgrp * 4;
#pragma unroll
    for (int n = 0; n < 4; ++n) {
      int c = n0 + wc * 64 + n * 16 + col;
#pragma unroll
      for (int i = 0; i < 4; ++i)
        O[(size_t)(r0 + i) * Ss + c] = acc[m][n][i] + bias;
    }
  }
}

extern "C" void kernel_launch(void* const* d_in, const int* in_sizes, int n_in,
                              void* d_out, int out_size, void* d_ws,
                              size_t ws_size, hipStream_t stream) {
  const float* batch = (const float*)d_in[0];  // [32][512][1024]
  const float* projL = (const float*)d_in[1];  // [1024][256]
  const float* projR = (const float*)d_in[2];  // [256][1024]
  const float* bias = (const float*)d_in[3];   // [1]
  float* out = (float*)d_out;                  // [32][512][512]

  char* ws = (char*)d_ws;
  __bf16* left = (__bf16*)(ws);                 // 8,388,608 B [16384][256]
  __bf16* right = (__bf16*)(ws + 8388608);      // 8,388,608 B [16384][256]
  __bf16* Btc = (__bf16*)(ws + 16777216);       // 1,048,576 B [512][1024]

  prep_kernel<<<dim3(2048), dim3(256), 0, stream>>>(projL, projR, Btc);
  proj_gemm<<<dim3(1024), dim3(256), 0, stream>>>(batch, Btc, left, right);
  score_gemm<<<dim3(4, 8, 32), dim3(256), 0, stream>>>(left, right, bias, out);
}